// Round 2
// baseline (430.037 us; speedup 1.0000x reference)
//
#include <hip/hip_runtime.h>
#include <stdint.h>

#define SEQ 4096
#define DM 1024

typedef __attribute__((ext_vector_type(8))) short short8;   // 8 bf16 = 4 VGPRs
typedef __attribute__((ext_vector_type(4))) float f32x4;

__device__ inline unsigned short f2bf(float f) {
  union { float f; uint32_t u; } v; v.f = f;
  return (unsigned short)((v.u + 0x7FFFu + ((v.u >> 16) & 1u)) >> 16);  // RNE
}
__device__ inline float bf2f(unsigned short h) {
  union { uint32_t u; float f; } v; v.u = ((uint32_t)h) << 16;
  return v.f;
}

// async global->LDS, 16B/lane; LDS dest = wave-uniform base + lane*16
__device__ inline void async_copy16(const void* g, void* lds) {
  __builtin_amdgcn_global_load_lds(
      (const __attribute__((address_space(1))) uint32_t*)g,
      (__attribute__((address_space(3))) uint32_t*)lds, 16, 0, 0);
}

// fp32 x [SEQ x DM] -> Xp bf16 [SEQ x 2*DM]: hi at col k, lo at col DM+k
__global__ __launch_bounds__(256)
void split_x(const float* __restrict__ x, unsigned short* __restrict__ Xp) {
  int idx = (blockIdx.x * 256 + threadIdx.x) * 4;
  int r = idx >> 10, c = idx & 1023;
  float4 v = *(const float4*)(x + idx);
  ushort4 hi, lo;
  hi.x = f2bf(v.x); lo.x = f2bf(v.x - bf2f(hi.x));
  hi.y = f2bf(v.y); lo.y = f2bf(v.y - bf2f(hi.y));
  hi.z = f2bf(v.z); lo.z = f2bf(v.z - bf2f(hi.z));
  hi.w = f2bf(v.w); lo.w = f2bf(v.w - bf2f(hi.w));
  *(ushort4*)(Xp + (size_t)r * 2048 + c) = hi;
  *(ushort4*)(Xp + (size_t)r * 2048 + 1024 + c) = lo;
}

// fp32 W [DM x DM] (k-major rows) -> Wp bf16 [DM x 2*DM], row n: hi(W[k][n]) at k, lo at DM+k
__global__ __launch_bounds__(256)
void splitT_w(const float* __restrict__ W, unsigned short* __restrict__ Wp) {
  __shared__ float tile[64][65];
  const int bn = blockIdx.x * 64, bk = blockIdx.y * 64;
  const int tx = threadIdx.x & 63, ty = threadIdx.x >> 6;
#pragma unroll
  for (int i = ty; i < 64; i += 4)
    tile[i][tx] = W[(size_t)(bk + i) * DM + bn + tx];
  __syncthreads();
#pragma unroll
  for (int i = ty; i < 64; i += 4) {
    float v = tile[tx][i];                    // W[bk+tx][bn+i]
    unsigned short h = f2bf(v);
    Wp[(size_t)(bn + i) * 2048 + bk + tx] = h;
    Wp[(size_t)(bn + i) * 2048 + 1024 + bk + tx] = f2bf(v - bf2f(h));
  }
}

// bf16 transpose with input row stride: in logical [R x 64*gridDim.x], out [C x R]
__global__ __launch_bounds__(256)
void transpose_bf16(const unsigned short* __restrict__ in, int istride,
                    unsigned short* __restrict__ out, int R) {
  __shared__ unsigned short tile[64][65];
  const int bc = blockIdx.x * 64, br = blockIdx.y * 64;
  const int tx = threadIdx.x & 63, ty = threadIdx.x >> 6;
#pragma unroll
  for (int i = ty; i < 64; i += 4)
    tile[i][tx] = in[(size_t)(br + i) * istride + bc + tx];
  __syncthreads();
#pragma unroll
  for (int i = ty; i < 64; i += 4)
    out[(size_t)(bc + i) * R + br + tx] = tile[tx][i];
}

// C[M,N] = scale * sum_ph A[:, offA+k] * Bt[:, offB+k]^T   (bf16 ops, fp32 acc)
// MODE 0: C fp32, plain.  MODE 1: C bf16 hi/lo pair, segmented:
//   idx = row*ldc + (col>>10)*2048 + (col&1023), lo at idx+1024.
template <int MODE>
__global__ __launch_bounds__(256)
void gemm_ph(const unsigned short* __restrict__ A, int lda,
             const unsigned short* __restrict__ Bt, int ldb,
             void* __restrict__ Cv, int ldc, int N, int Kp, int nph,
             int oA0, int oB0, int oA1, int oB1, int oA2, int oB2,
             float scale) {
  __shared__ unsigned short As[128 * 32];
  __shared__ unsigned short Bs[128 * 32];
  const int t = threadIdx.x;
  const int wave = t >> 6, lane = t & 63;
  const int quad = lane >> 4, l16 = lane & 15;
  const int m0 = blockIdx.y * 128, n0 = blockIdx.x * 128;
  const int wm = (wave & 1) * 64, wn = (wave >> 1) * 64;
  const int srow = lane >> 2;        // row within 16-row staging chunk
  const int scol = (lane & 3) * 8;   // bf16 offset along K (16B)

  f32x4 acc[4][4] = {};

  for (int ph = 0; ph < nph; ++ph) {
    const int ka = (ph == 0) ? oA0 : (ph == 1) ? oA1 : oA2;
    const int kb = (ph == 0) ? oB0 : (ph == 1) ? oB1 : oB2;
    const unsigned short* Ap = A + ka;
    const unsigned short* Bp = Bt + kb;
    for (int k0 = 0; k0 < Kp; k0 += 32) {
#pragma unroll
      for (int i = 0; i < 2; ++i) {
        int c = wave * 2 + i;  // wave-uniform chunk id
        async_copy16(Ap + (size_t)(m0 + c * 16 + srow) * lda + k0 + scol,
                     As + c * 512);
        async_copy16(Bp + (size_t)(n0 + c * 16 + srow) * ldb + k0 + scol,
                     Bs + c * 512);
      }
      __syncthreads();
      short8 af[4], bfr[4];
#pragma unroll
      for (int i = 0; i < 4; ++i) {
        af[i]  = *(const short8*)(As + (wm + i * 16 + l16) * 32 + quad * 8);
        bfr[i] = *(const short8*)(Bs + (wn + i * 16 + l16) * 32 + quad * 8);
      }
#pragma unroll
      for (int i = 0; i < 4; ++i)
#pragma unroll
        for (int j = 0; j < 4; ++j)
          acc[i][j] = __builtin_amdgcn_mfma_f32_16x16x32_bf16(
              af[i], bfr[j], acc[i][j], 0, 0, 0);
      __syncthreads();
    }
  }

  // C/D layout: col = l16, row = quad*4 + r
#pragma unroll
  for (int i = 0; i < 4; ++i)
#pragma unroll
    for (int j = 0; j < 4; ++j)
#pragma unroll
      for (int r = 0; r < 4; ++r) {
        int row = m0 + wm + i * 16 + quad * 4 + r;
        int col = n0 + wn + j * 16 + l16;
        float v = acc[i][j][r] * scale;
        if (MODE == 0) {
          ((float*)Cv)[(size_t)row * ldc + col] = v;
        } else {
          unsigned short* C = (unsigned short*)Cv;
          size_t base = (size_t)row * ldc + ((col >> 10) << 11) + (col & 1023);
          unsigned short h = f2bf(v);
          C[base] = h;
          C[base + 1024] = f2bf(v - bf2f(h));
        }
      }
}

// one block per row; fp32 scores row (stride SEQ), writes bf16 probs in place
__global__ __launch_bounds__(256)
void softmax_rows(float* __restrict__ S) {
  const int row = blockIdx.x;
  const int t = threadIdx.x, lane = t & 63, wave = t >> 6;
  float* srow = S + (size_t)row * SEQ;
  const float4* s4 = (const float4*)srow;
  float4 v[4];
  float m = -3.4e38f;
#pragma unroll
  for (int i = 0; i < 4; ++i) {
    v[i] = s4[i * 256 + t];
    m = fmaxf(m, fmaxf(fmaxf(v[i].x, v[i].y), fmaxf(v[i].z, v[i].w)));
  }
  __shared__ float redm[4], reds[4];
#pragma unroll
  for (int o = 32; o; o >>= 1) m = fmaxf(m, __shfl_xor(m, o));
  if (lane == 0) redm[wave] = m;
  __syncthreads();
  m = fmaxf(fmaxf(redm[0], redm[1]), fmaxf(redm[2], redm[3]));
  float sum = 0.f;
#pragma unroll
  for (int i = 0; i < 4; ++i) {
    v[i].x = __expf(v[i].x - m); v[i].y = __expf(v[i].y - m);
    v[i].z = __expf(v[i].z - m); v[i].w = __expf(v[i].w - m);
    sum += v[i].x + v[i].y + v[i].z + v[i].w;
  }
#pragma unroll
  for (int o = 32; o; o >>= 1) sum += __shfl_xor(sum, o);
  if (lane == 0) reds[wave] = sum;
  __syncthreads();
  const float inv = 1.f / (reds[0] + reds[1] + reds[2] + reds[3]);
  ushort4* p4 = (ushort4*)srow;  // bf16 row occupies first half of fp32 row
#pragma unroll
  for (int i = 0; i < 4; ++i) {
    ushort4 o;
    o.x = f2bf(v[i].x * inv); o.y = f2bf(v[i].y * inv);
    o.z = f2bf(v[i].z * inv); o.w = f2bf(v[i].w * inv);
    p4[i * 256 + t] = o;
  }
}

extern "C" void kernel_launch(void* const* d_in, const int* in_sizes, int n_in,
                              void* d_out, int out_size, void* d_ws, size_t ws_size,
                              hipStream_t stream) {
  const float* x  = (const float*)d_in[0];
  const float* Wq = (const float*)d_in[1];
  const float* Wk = (const float*)d_in[2];
  const float* Wv = (const float*)d_in[3];
  float* out = (float*)d_out;
  char* ws = (char*)d_ws;
  const size_t MB = (size_t)1 << 20;
  // ws layout (148 MB total):
  unsigned short* Xp   = (unsigned short*)(ws + 0 * MB);   // 16 MB [SEQ x 2048]
  unsigned short* Wall = (unsigned short*)(ws + 16 * MB);  // 12 MB [3072 x 2048]
  unsigned short* QKV  = (unsigned short*)(ws + 28 * MB);  // 48 MB [SEQ x 6144]
  unsigned short* VT   = (unsigned short*)(ws + 76 * MB);  //  8 MB [DM x SEQ]
  float*          S    = (float*)(ws + 84 * MB);           // 64 MB [SEQ x SEQ]

  // 1) split inputs into bf16 hi/lo pairs (W also transposed to [n][k])
  split_x<<<SEQ * DM / 1024, 256, 0, stream>>>(x, Xp);
  splitT_w<<<dim3(16, 16), 256, 0, stream>>>(Wq, Wall + (size_t)0 * DM * 2048);
  splitT_w<<<dim3(16, 16), 256, 0, stream>>>(Wk, Wall + (size_t)1 * DM * 2048);
  splitT_w<<<dim3(16, 16), 256, 0, stream>>>(Wv, Wall + (size_t)2 * DM * 2048);

  // 2) fused QKV projection: [SEQ x 3072] outputs as hi/lo pairs (3 phases)
  gemm_ph<1><<<dim3(3 * DM / 128, SEQ / 128), 256, 0, stream>>>(
      Xp, 2048, Wall, 2048, QKV, 6144, 3 * DM, DM, 3,
      0, 0, 0, 1024, 1024, 0, 1.0f);

  // 3) V^T (from V-hi segment at column offset 4096)
  transpose_bf16<<<dim3(DM / 64, SEQ / 64), 256, 0, stream>>>(
      QKV + 4096, 6144, VT, SEQ);

  // 4) scores = Q K^T / 32, fp32 (3 phases of hi/lo)
  gemm_ph<0><<<dim3(SEQ / 128, SEQ / 128), 256, 0, stream>>>(
      QKV, 6144, QKV + 2048, 6144, S, SEQ, SEQ, DM, 3,
      0, 0, 0, 1024, 1024, 0, 0.03125f);

  // 5) row softmax, bf16 P written in place (P row stride = 2*SEQ bf16)
  softmax_rows<<<SEQ, 256, 0, stream>>>(S);

  // 6) out = P V, fp32 output
  gemm_ph<0><<<dim3(DM / 128, SEQ / 128), 256, 0, stream>>>(
      (const unsigned short*)S, 2 * SEQ, VT, SEQ, out, DM, DM, SEQ, 1,
      0, 0, 0, 0, 0, 0, 1.0f);
}

// Round 3
// 367.802 us; speedup vs baseline: 1.1692x; 1.1692x over previous
//
#include <hip/hip_runtime.h>
#include <stdint.h>

#define SEQ 4096
#define DM 1024

typedef __attribute__((ext_vector_type(8))) short short8;   // 8 bf16 = 4 VGPRs
typedef __attribute__((ext_vector_type(4))) float f32x4;
typedef unsigned short ushort_t;

__device__ inline ushort_t f2bf(float f) {
  union { float f; uint32_t u; } v; v.f = f;
  return (ushort_t)((v.u + 0x7FFFu + ((v.u >> 16) & 1u)) >> 16);  // RNE
}
__device__ inline float bf2f(ushort_t h) {
  union { uint32_t u; float f; } v; v.u = ((uint32_t)h) << 16;
  return v.f;
}

// async global->LDS, 16B/lane; LDS dest = wave-uniform base + lane*16
__device__ inline void async_copy16(const void* g, void* lds) {
  __builtin_amdgcn_global_load_lds(
      (const __attribute__((address_space(1))) uint32_t*)g,
      (__attribute__((address_space(3))) uint32_t*)lds, 16, 0, 0);
}

// fp32 x [SEQ x DM] -> Xp bf16 [SEQ x 2*DM]: hi at col k, lo at col DM+k
__global__ __launch_bounds__(256)
void split_x(const float* __restrict__ x, ushort_t* __restrict__ Xp) {
  int idx = (blockIdx.x * 256 + threadIdx.x) * 4;
  int r = idx >> 10, c = idx & 1023;
  float4 v = *(const float4*)(x + idx);
  ushort4 hi, lo;
  hi.x = f2bf(v.x); lo.x = f2bf(v.x - bf2f(hi.x));
  hi.y = f2bf(v.y); lo.y = f2bf(v.y - bf2f(hi.y));
  hi.z = f2bf(v.z); lo.z = f2bf(v.z - bf2f(hi.z));
  hi.w = f2bf(v.w); lo.w = f2bf(v.w - bf2f(hi.w));
  *(ushort4*)(Xp + (size_t)r * 2048 + c) = hi;
  *(ushort4*)(Xp + (size_t)r * 2048 + 1024 + c) = lo;
}

// fp32 W [DM x DM] -> Wp bf16 [DM x 2048], row n: hi(W[k][n]) at k, lo at 1024+k
__global__ __launch_bounds__(256)
void splitT_w(const float* __restrict__ W, ushort_t* __restrict__ Wp) {
  __shared__ float tile[64][65];
  const int bn = blockIdx.x * 64, bk = blockIdx.y * 64;
  const int tx = threadIdx.x & 63, ty = threadIdx.x >> 6;
#pragma unroll
  for (int i = ty; i < 64; i += 4)
    tile[i][tx] = W[(size_t)(bk + i) * DM + bn + tx];
  __syncthreads();
#pragma unroll
  for (int i = ty; i < 64; i += 4) {
    float v = tile[tx][i];                    // W[bk+tx][bn+i]
    ushort_t h = f2bf(v);
    Wp[(size_t)(bn + i) * 2048 + bk + tx] = h;
    Wp[(size_t)(bn + i) * 2048 + 1024 + bk + tx] = f2bf(v - bf2f(h));
  }
}

// bf16 transpose: in [R x *] with row stride istride, out [C x R]
__global__ __launch_bounds__(256)
void transpose_bf16(const ushort_t* __restrict__ in, int istride,
                    ushort_t* __restrict__ out, int R) {
  __shared__ ushort_t tile[64][65];
  const int bc = blockIdx.x * 64, br = blockIdx.y * 64;
  const int tx = threadIdx.x & 63, ty = threadIdx.x >> 6;
#pragma unroll
  for (int i = ty; i < 64; i += 4)
    tile[i][tx] = in[(size_t)(br + i) * istride + bc + tx];
  __syncthreads();
#pragma unroll
  for (int i = ty; i < 64; i += 4)
    out[(size_t)(bc + i) * R + br + tx] = tile[tx][i];
}

// Fused 3-phase split-bf16 GEMM:
//   C[M,N] = scale * (Ah*Bh^T + Ah*Bl^T + Al*Bh^T), fp32 acc.
// A rows [lda=2048]: hi at k, lo at 1024+k. Bt rows likewise.
// Per k-chunk: stage all 4 tiles (32 KB LDS), 48 MFMA per barrier-pair.
// MODE 0: C fp32 (ldc cols). MODE 1: C = hi/lo bf16 into Q/K/V segment buffers.
template <int MODE>
__global__ __launch_bounds__(256, 3)
void gemm_f3(const ushort_t* __restrict__ A, const ushort_t* __restrict__ Bt,
             void* __restrict__ Cv, ushort_t* __restrict__ O1,
             ushort_t* __restrict__ O2, int ldc, float scale) {
  __shared__ ushort_t As[2][128 * 32];
  __shared__ ushort_t Bs[2][128 * 32];
  const int t = threadIdx.x;
  const int wave = t >> 6, lane = t & 63;
  const int quad = lane >> 4, l16 = lane & 15;
  const int m0 = blockIdx.y * 128, n0 = blockIdx.x * 128;
  const int wm = (wave & 1) * 64, wn = (wave >> 1) * 64;
  const int srow = lane >> 2;        // row within 16-row staging chunk
  const int scol = (lane & 3) * 8;   // bf16 offset along K (16B)

  f32x4 acc[4][4] = {};

  for (int k0 = 0; k0 < 1024; k0 += 32) {
#pragma unroll
    for (int i = 0; i < 2; ++i) {
      int c = wave * 2 + i;  // wave-uniform chunk id
      const ushort_t* ga = A + (size_t)(m0 + c * 16 + srow) * 2048 + k0 + scol;
      const ushort_t* gb = Bt + (size_t)(n0 + c * 16 + srow) * 2048 + k0 + scol;
      async_copy16(ga,        As[0] + c * 512);
      async_copy16(ga + 1024, As[1] + c * 512);
      async_copy16(gb,        Bs[0] + c * 512);
      async_copy16(gb + 1024, Bs[1] + c * 512);
    }
    __syncthreads();
    short8 a[4], b[4], cl[4];
#pragma unroll
    for (int i = 0; i < 4; ++i) {
      a[i] = *(const short8*)(As[0] + (wm + i * 16 + l16) * 32 + quad * 8);
      b[i] = *(const short8*)(Bs[0] + (wn + i * 16 + l16) * 32 + quad * 8);
    }
#pragma unroll
    for (int i = 0; i < 4; ++i)
#pragma unroll
      for (int j = 0; j < 4; ++j)
        acc[i][j] = __builtin_amdgcn_mfma_f32_16x16x32_bf16(a[i], b[j], acc[i][j], 0, 0, 0);
#pragma unroll
    for (int j = 0; j < 4; ++j)
      cl[j] = *(const short8*)(Bs[1] + (wn + j * 16 + l16) * 32 + quad * 8);
#pragma unroll
    for (int i = 0; i < 4; ++i)
#pragma unroll
      for (int j = 0; j < 4; ++j)
        acc[i][j] = __builtin_amdgcn_mfma_f32_16x16x32_bf16(a[i], cl[j], acc[i][j], 0, 0, 0);
#pragma unroll
    for (int i = 0; i < 4; ++i)
      a[i] = *(const short8*)(As[1] + (wm + i * 16 + l16) * 32 + quad * 8);
#pragma unroll
    for (int i = 0; i < 4; ++i)
#pragma unroll
      for (int j = 0; j < 4; ++j)
        acc[i][j] = __builtin_amdgcn_mfma_f32_16x16x32_bf16(a[i], b[j], acc[i][j], 0, 0, 0);
    __syncthreads();
  }

  if (MODE == 1) {
    // Q/K/V segment: 128-col block never straddles a 1024 boundary
    ushort_t* Cm = (n0 < 1024) ? (ushort_t*)Cv : (n0 < 2048) ? O1 : O2;
    const int cb = n0 & 1023;
#pragma unroll
    for (int i = 0; i < 4; ++i)
#pragma unroll
      for (int j = 0; j < 4; ++j)
#pragma unroll
        for (int r = 0; r < 4; ++r) {
          int row = m0 + wm + i * 16 + quad * 4 + r;
          int col = cb + wn + j * 16 + l16;
          float v = acc[i][j][r];
          ushort_t h = f2bf(v);
          size_t base = (size_t)row * 2048 + col;
          Cm[base] = h;
          Cm[base + 1024] = f2bf(v - bf2f(h));
        }
  } else {
#pragma unroll
    for (int i = 0; i < 4; ++i)
#pragma unroll
      for (int j = 0; j < 4; ++j)
#pragma unroll
        for (int r = 0; r < 4; ++r) {
          int row = m0 + wm + i * 16 + quad * 4 + r;
          int col = n0 + wn + j * 16 + l16;
          ((float*)Cv)[(size_t)row * ldc + col] = acc[i][j][r] * scale;
        }
  }
}

// PV: C[M=SEQ, N=DM] += A[M, k-range] * Bt[N, k-range]^T, split-K via blockIdx.z,
// fp32 atomicAdd epilogue (d_out pre-zeroed). A = P bf16 (lda), Bt = VT (ldb=SEQ).
__global__ __launch_bounds__(256)
void gemm_pv(const ushort_t* __restrict__ A, int lda,
             const ushort_t* __restrict__ Bt,
             float* __restrict__ C) {
  __shared__ ushort_t As[128 * 32];
  __shared__ ushort_t Bs[128 * 32];
  const int t = threadIdx.x;
  const int wave = t >> 6, lane = t & 63;
  const int quad = lane >> 4, l16 = lane & 15;
  const int m0 = blockIdx.y * 128, n0 = blockIdx.x * 128;
  const int wm = (wave & 1) * 64, wn = (wave >> 1) * 64;
  const int srow = lane >> 2, scol = (lane & 3) * 8;
  const int kbeg = blockIdx.z * 2048, kend = kbeg + 2048;

  f32x4 acc[4][4] = {};
  for (int k0 = kbeg; k0 < kend; k0 += 32) {
#pragma unroll
    for (int i = 0; i < 2; ++i) {
      int c = wave * 2 + i;
      async_copy16(A + (size_t)(m0 + c * 16 + srow) * lda + k0 + scol, As + c * 512);
      async_copy16(Bt + (size_t)(n0 + c * 16 + srow) * SEQ + k0 + scol, Bs + c * 512);
    }
    __syncthreads();
    short8 a[4], b[4];
#pragma unroll
    for (int i = 0; i < 4; ++i) {
      a[i] = *(const short8*)(As + (wm + i * 16 + l16) * 32 + quad * 8);
      b[i] = *(const short8*)(Bs + (wn + i * 16 + l16) * 32 + quad * 8);
    }
#pragma unroll
    for (int i = 0; i < 4; ++i)
#pragma unroll
      for (int j = 0; j < 4; ++j)
        acc[i][j] = __builtin_amdgcn_mfma_f32_16x16x32_bf16(a[i], b[j], acc[i][j], 0, 0, 0);
    __syncthreads();
  }
#pragma unroll
  for (int i = 0; i < 4; ++i)
#pragma unroll
    for (int j = 0; j < 4; ++j)
#pragma unroll
      for (int r = 0; r < 4; ++r) {
        int row = m0 + wm + i * 16 + quad * 4 + r;
        int col = n0 + wn + j * 16 + l16;
        atomicAdd(C + (size_t)row * DM + col, acc[i][j][r]);
      }
}

// one block per row; fp32 scores row (stride SEQ), writes bf16 probs in place
__global__ __launch_bounds__(256)
void softmax_rows(float* __restrict__ S) {
  const int row = blockIdx.x;
  const int t = threadIdx.x, lane = t & 63, wave = t >> 6;
  float* srow = S + (size_t)row * SEQ;
  const float4* s4 = (const float4*)srow;
  float4 v[4];
  float m = -3.4e38f;
#pragma unroll
  for (int i = 0; i < 4; ++i) {
    v[i] = s4[i * 256 + t];
    m = fmaxf(m, fmaxf(fmaxf(v[i].x, v[i].y), fmaxf(v[i].z, v[i].w)));
  }
  __shared__ float redm[4], reds[4];
#pragma unroll
  for (int o = 32; o; o >>= 1) m = fmaxf(m, __shfl_xor(m, o));
  if (lane == 0) redm[wave] = m;
  __syncthreads();
  m = fmaxf(fmaxf(redm[0], redm[1]), fmaxf(redm[2], redm[3]));
  float sum = 0.f;
#pragma unroll
  for (int i = 0; i < 4; ++i) {
    v[i].x = __expf(v[i].x - m); v[i].y = __expf(v[i].y - m);
    v[i].z = __expf(v[i].z - m); v[i].w = __expf(v[i].w - m);
    sum += v[i].x + v[i].y + v[i].z + v[i].w;
  }
#pragma unroll
  for (int o = 32; o; o >>= 1) sum += __shfl_xor(sum, o);
  if (lane == 0) reds[wave] = sum;
  __syncthreads();
  const float inv = 1.f / (reds[0] + reds[1] + reds[2] + reds[3]);
  ushort4* p4 = (ushort4*)srow;  // bf16 row occupies first half of fp32 row
#pragma unroll
  for (int i = 0; i < 4; ++i) {
    ushort4 o;
    o.x = f2bf(v[i].x * inv); o.y = f2bf(v[i].y * inv);
    o.z = f2bf(v[i].z * inv); o.w = f2bf(v[i].w * inv);
    p4[i * 256 + t] = o;
  }
}

extern "C" void kernel_launch(void* const* d_in, const int* in_sizes, int n_in,
                              void* d_out, int out_size, void* d_ws, size_t ws_size,
                              hipStream_t stream) {
  const float* x  = (const float*)d_in[0];
  const float* Wq = (const float*)d_in[1];
  const float* Wk = (const float*)d_in[2];
  const float* Wv = (const float*)d_in[3];
  float* out = (float*)d_out;
  char* ws = (char*)d_ws;
  const size_t MB = (size_t)1 << 20;
  // ws layout (148 MB):
  ushort_t* Xp   = (ushort_t*)(ws + 0 * MB);    // 16 MB [SEQ x 2048] hi|lo
  ushort_t* Wall = (ushort_t*)(ws + 16 * MB);   // 12 MB [3072 x 2048]
  ushort_t* Qb   = (ushort_t*)(ws + 28 * MB);   // 16 MB [SEQ x 2048]
  ushort_t* Kb   = (ushort_t*)(ws + 44 * MB);   // 16 MB
  ushort_t* Vb   = (ushort_t*)(ws + 60 * MB);   // 16 MB
  ushort_t* VT   = (ushort_t*)(ws + 76 * MB);   //  8 MB [DM x SEQ] (hi only)
  float*    S    = (float*)(ws + 84 * MB);      // 64 MB [SEQ x SEQ]

  hipMemsetAsync(d_out, 0, (size_t)SEQ * DM * sizeof(float), stream);

  // 1) split inputs into bf16 hi/lo pairs (W transposed to [n][k])
  split_x<<<SEQ * DM / 1024, 256, 0, stream>>>(x, Xp);
  splitT_w<<<dim3(16, 16), 256, 0, stream>>>(Wq, Wall + (size_t)0 * DM * 2048);
  splitT_w<<<dim3(16, 16), 256, 0, stream>>>(Wk, Wall + (size_t)1 * DM * 2048);
  splitT_w<<<dim3(16, 16), 256, 0, stream>>>(Wv, Wall + (size_t)2 * DM * 2048);

  // 2) fused QKV projection -> Qb, Kb, Vb (hi/lo pairs)
  gemm_f3<1><<<dim3(3 * DM / 128, SEQ / 128), 256, 0, stream>>>(
      Xp, Wall, Qb, Kb, Vb, 0, 1.0f);

  // 3) V^T (hi segment)
  transpose_bf16<<<dim3(DM / 64, SEQ / 64), 256, 0, stream>>>(Vb, 2048, VT, SEQ);

  // 4) scores = Q K^T / 32, fp32
  gemm_f3<0><<<dim3(SEQ / 128, SEQ / 128), 256, 0, stream>>>(
      Qb, Kb, S, nullptr, nullptr, SEQ, 0.03125f);

  // 5) row softmax, bf16 P written in place (P row stride = 2*SEQ bf16)
  softmax_rows<<<SEQ, 256, 0, stream>>>(S);

  // 6) out = P V, split-K=2, atomic fp32 accumulate
  gemm_pv<<<dim3(DM / 128, SEQ / 128, 2), 256, 0, stream>>>(
      (const ushort_t*)S, 2 * SEQ, VT, out);
}